// Round 1
// baseline (864.125 us; speedup 1.0000x reference)
//
#include <hip/hip_runtime.h>

// CausalWindowedAttention: B=2,H=16,S=2048,D=64, window=256, temp=8
// Outputs: out [B,H,S,D] fp32, attn [B,H,S,S] fp32 (concatenated in d_out).
// Store-BW-bound (536 MB attn write). One block = 16 query rows.

#define S_LEN 2048
#define DHEAD 64
#define TQ 16
#define UEXT 272      // staged key-column extent per block: j in [i0-256, i0+16)
#define SC_STRIDE 276 // halfs; 552 B rows (8B aligned), bank-friendly
#define KV_STRIDE 72  // halfs; 144 B rows (16B aligned), pad breaks bank stride
#define PO_STRIDE 68  // halfs

typedef float     f4v __attribute__((ext_vector_type(4)));
typedef _Float16  h2v __attribute__((ext_vector_type(2)));
typedef _Float16  h4v __attribute__((ext_vector_type(4)));

__device__ __forceinline__ float dot2f(float aBits, float bBits, float c) {
#if __has_builtin(__builtin_amdgcn_fdot2)
  return __builtin_amdgcn_fdot2(__builtin_bit_cast(h2v, aBits),
                                __builtin_bit_cast(h2v, bBits), c, false);
#else
  h2v a = __builtin_bit_cast(h2v, aBits);
  h2v b = __builtin_bit_cast(h2v, bBits);
  return c + (float)a.x * (float)b.x + (float)a.y * (float)b.y;
#endif
}

__global__ __launch_bounds__(256, 2)
void cwa_kernel(const float* __restrict__ q, const float* __restrict__ k,
                const float* __restrict__ v, float* __restrict__ out,
                float* __restrict__ attn)
{
  __shared__ __align__(16) _Float16 kv[UEXT][KV_STRIDE];  // K window, then V window
  __shared__ __align__(16) _Float16 kq[TQ][DHEAD];        // Q tile (f16)
  __shared__ __align__(16) _Float16 sc[TQ][SC_STRIDE];    // unnormalized exp scores
  __shared__ __align__(16) _Float16 po[4][TQ][PO_STRIDE]; // per-wave PV partials
  __shared__ float rsum[4][TQ];
  __shared__ float rinv[TQ];

  const int t    = threadIdx.x;
  const int lane = t & 63;
  const int wv   = t >> 6;       // wave 0..3
  const int trow = lane >> 4;    // 0..3
  const int tcol = lane & 15;    // 0..15

  const int blk   = blockIdx.x;
  const int bh    = blk >> 7;          // / 128 tiles
  const int i0    = (blk & 127) * TQ;  // first query row of tile
  const int jbase = i0 - 256;          // global key row of staged column u=0

  const size_t base = (size_t)bh * (S_LEN * DHEAD);
  const float* qb = q + base;
  const float* kb = k + base;
  const float* vb = v + base;

  const f4v fzero = {0.f, 0.f, 0.f, 0.f};

  // ---------------- P0: stage Q tile + K window as f16 ----------------
  {
    const int r = t >> 4, d4 = t & 15;
    f4v f = *(const f4v*)(qb + (size_t)(i0 + r) * DHEAD + 4 * d4);
    h4v h = { (_Float16)f.x, (_Float16)f.y, (_Float16)f.z, (_Float16)f.w };
    *(h4v*)&kq[r][4 * d4] = h;
  }
  #pragma unroll 4
  for (int w = 0; w < 17; ++w) {
    const int idx = t + 256 * w;       // 0..4351
    const int u = idx >> 4, d4 = idx & 15;
    const int j = jbase + u;
    f4v f = fzero;                      // zero-fill OOB rows (avoid NaN garbage)
    if (j >= 0 && j < S_LEN) f = *(const f4v*)(kb + (size_t)j * DHEAD + 4 * d4);
    h4v h = { (_Float16)f.x, (_Float16)f.y, (_Float16)f.z, (_Float16)f.w };
    *(h4v*)&kv[u][4 * d4] = h;
  }
  __syncthreads();

  // ---------------- P1: QK^T (f16 dot2), mask, exp, row sums ----------------
  {
    float acc[4][5];
    #pragma unroll
    for (int i = 0; i < 4; ++i)
      #pragma unroll
      for (int j = 0; j < 5; ++j) acc[i][j] = 0.f;

    const int cbase = 68 * wv + tcol;  // wave owns columns [68*wv, 68*wv+68)

    for (int ds2 = 0; ds2 < 8; ++ds2) {
      f4v qr[4], kr[5];
      #pragma unroll
      for (int i = 0; i < 4; ++i)
        qr[i] = *(const f4v*)&kq[trow + 4 * i][8 * ds2];
      #pragma unroll
      for (int j = 0; j < 4; ++j)
        kr[j] = *(const f4v*)&kv[cbase + 16 * j][8 * ds2];
      kr[4] = (tcol < 4) ? *(const f4v*)&kv[cbase + 64][8 * ds2] : fzero;

      #pragma unroll
      for (int i = 0; i < 4; ++i) {
        #pragma unroll
        for (int j = 0; j < 5; ++j) {
          float a = acc[i][j];
          a = dot2f(qr[i].x, kr[j].x, a);
          a = dot2f(qr[i].y, kr[j].y, a);
          a = dot2f(qr[i].z, kr[j].z, a);
          a = dot2f(qr[i].w, kr[j].w, a);
          acc[i][j] = a;
        }
      }
    }

    float rs[4] = {0.f, 0.f, 0.f, 0.f};
    #pragma unroll
    for (int i = 0; i < 4; ++i) {
      const int r = trow + 4 * i;
      #pragma unroll
      for (int j = 0; j < 5; ++j) {
        if (j == 4 && tcol >= 4) continue;   // only tcol<4 own a 5th column
        const int u = cbase + 16 * j;
        // window: u in [r+1, r+256]; j_global >= 0 <=> u >= 256 - i0
        const bool valid = (u >= r + 1) && (u <= r + 256) && (u >= 256 - i0);
        const float p = valid ? __expf(acc[i][j] * 0.125f) : 0.f;
        sc[r][u] = (_Float16)p;
        rs[i] += p;
      }
    }
    // reduce over the 16-lane column group
    #pragma unroll
    for (int off = 8; off > 0; off >>= 1) {
      #pragma unroll
      for (int i = 0; i < 4; ++i) rs[i] += __shfl_down(rs[i], off, 64);
    }
    if (tcol == 0) {
      #pragma unroll
      for (int i = 0; i < 4; ++i) rsum[wv][trow + 4 * i] = rs[i];
    }
  }
  __syncthreads();

  // ---------------- P2: stage V (overwrites kv) + 1/rowsum ----------------
  #pragma unroll 4
  for (int w = 0; w < 17; ++w) {
    const int idx = t + 256 * w;
    const int u = idx >> 4, d4 = idx & 15;
    const int j = jbase + u;
    f4v f = fzero;
    if (j >= 0 && j < S_LEN) f = *(const f4v*)(vb + (size_t)j * DHEAD + 4 * d4);
    h4v h = { (_Float16)f.x, (_Float16)f.y, (_Float16)f.z, (_Float16)f.w };
    *(h4v*)&kv[u][4 * d4] = h;
  }
  if (t < TQ) {
    rinv[t] = 1.f / (rsum[0][t] + rsum[1][t] + rsum[2][t] + rsum[3][t]);
  }
  __syncthreads();

  // ---------------- P3: PV partials (u-range split across waves) ----------------
  {
    f4v acc4[4];
    #pragma unroll
    for (int i = 0; i < 4; ++i) acc4[i] = fzero;
    const int u0 = 68 * wv;

    for (int st = 0; st < 17; ++st) {
      const int u = u0 + 4 * st;
      f4v vv[4];
      #pragma unroll
      for (int e = 0; e < 4; ++e) {
        h4v vh = *(const h4v*)&kv[u + e][4 * tcol];
        f4v fv = { (float)vh.x, (float)vh.y, (float)vh.z, (float)vh.w };
        vv[e] = fv;
      }
      #pragma unroll
      for (int i = 0; i < 4; ++i) {
        h4v ph = *(const h4v*)&sc[trow + 4 * i][u];
        const float p0 = (float)ph.x, p1 = (float)ph.y;
        const float p2 = (float)ph.z, p3 = (float)ph.w;
        f4v a = acc4[i];
        a.x = fmaf(p0, vv[0].x, a.x); a.y = fmaf(p0, vv[0].y, a.y);
        a.z = fmaf(p0, vv[0].z, a.z); a.w = fmaf(p0, vv[0].w, a.w);
        a.x = fmaf(p1, vv[1].x, a.x); a.y = fmaf(p1, vv[1].y, a.y);
        a.z = fmaf(p1, vv[1].z, a.z); a.w = fmaf(p1, vv[1].w, a.w);
        a.x = fmaf(p2, vv[2].x, a.x); a.y = fmaf(p2, vv[2].y, a.y);
        a.z = fmaf(p2, vv[2].z, a.z); a.w = fmaf(p2, vv[2].w, a.w);
        a.x = fmaf(p3, vv[3].x, a.x); a.y = fmaf(p3, vv[3].y, a.y);
        a.z = fmaf(p3, vv[3].z, a.z); a.w = fmaf(p3, vv[3].w, a.w);
        acc4[i] = a;
      }
    }
    #pragma unroll
    for (int i = 0; i < 4; ++i) {
      h4v h = { (_Float16)acc4[i].x, (_Float16)acc4[i].y,
                (_Float16)acc4[i].z, (_Float16)acc4[i].w };
      *(h4v*)&po[wv][trow + 4 * i][4 * tcol] = h;
    }
  }
  __syncthreads();

  // ---------------- P4: final out + full attn row writes ----------------
  {
    const int r = t >> 4, d4 = t & 15;
    f4v o = fzero;
    #pragma unroll
    for (int w2 = 0; w2 < 4; ++w2) {
      h4v pw = *(const h4v*)&po[w2][r][4 * d4];
      o.x += (float)pw.x; o.y += (float)pw.y;
      o.z += (float)pw.z; o.w += (float)pw.w;
    }
    const float inv = rinv[r];
    o.x *= inv; o.y *= inv; o.z *= inv; o.w *= inv;
    __builtin_nontemporal_store(o,
        (f4v*)(out + (size_t)(bh * S_LEN + i0 + r) * DHEAD + 4 * d4));
  }

  float* abase = attn + (size_t)(bh * S_LEN + i0) * S_LEN;
  for (int w3 = 0; w3 < 32; ++w3) {
    const int flat = t + 256 * w3;       // 0..8191 (16 rows x 512 float4)
    const int r  = flat >> 9;
    const int u4 = flat & 511;
    const int ir = i0 + r;
    const float inv = rinv[r];
    const int j0 = 4 * u4;
    float va[4];
    #pragma unroll
    for (int c = 0; c < 4; ++c) {
      const int jc = j0 + c;
      int u = jc - jbase;
      u = u < 1 ? 1 : (u > 271 ? 271 : u);   // clamp (discarded when out-of-band)
      const bool in = (jc <= ir) && (jc > ir - 256);
      va[c] = in ? (float)sc[r][u] * inv : 0.f;
    }
    f4v val = { va[0], va[1], va[2], va[3] };
    __builtin_nontemporal_store(val, (f4v*)(abase + (size_t)r * S_LEN + j0));
  }
}

extern "C" void kernel_launch(void* const* d_in, const int* in_sizes, int n_in,
                              void* d_out, int out_size, void* d_ws, size_t ws_size,
                              hipStream_t stream) {
  const float* q = (const float*)d_in[0];
  const float* k = (const float*)d_in[1];
  const float* v = (const float*)d_in[2];
  float* out  = (float*)d_out;
  float* attn = out + (size_t)2 * 16 * 2048 * 64;   // out first, then attn

  dim3 grid(4096), block(256);                      // 32 bh * 128 tiles
  hipLaunchKernelGGL(cwa_kernel, grid, block, 0, stream, q, k, v, out, attn);
}